// Round 11
// baseline (149.928 us; speedup 1.0000x reference)
//
#include <hip/hip_runtime.h>

#define N_NODES 50000
#define N_EDGES 600000
#define N_REL 8
#define D_IN 128
#define D_OUT 16
#define NC 144   // 8 relation col-groups + root

typedef __attribute__((ext_vector_type(8))) short bf16x8;
typedef __attribute__((ext_vector_type(4))) float f32x4;
typedef __attribute__((ext_vector_type(8))) unsigned short u16x8;

#define COUNT_BLOCKS ((N_EDGES + 255) / 256)        // 2344
#define WB_BLOCKS    ((NC * D_IN) / 256)            // 72 (exact)
#define K0_BLOCKS    (COUNT_BLOCKS + WB_BLOCKS)     // 2416
#define GEMM_BLOCKS  ((N_NODES + 63) / 64)          // 782 (64 nodes/block)
#define EDGE_BLOCKS  ((N_EDGES / 64 + 3) / 4)       // 2344 (64 edges/wave)

__device__ __forceinline__ unsigned short f2bf(float f) {  // RNE
    unsigned u = __float_as_uint(f);
    return (unsigned short)((u + 0x7FFF + ((u >> 16) & 1)) >> 16);
}
__device__ __forceinline__ float bf2f(unsigned short h) {
    return __uint_as_float((unsigned)h << 16);
}
// LDS swizzle: row c = byte>>8 (256 B rows); XOR (c&7)<<4 keeps 16B align.
__device__ __forceinline__ int swz(int byte) { return byte ^ (((byte >> 8) & 7) << 4); }

// -------- k0: {edge-count blocks} + {pre-swizzled W build} in one grid ------
// WallT_pre holds bf16 W/root in the EXACT byte permutation k1's LDS wants,
// so k1 can stage it with linear vector copies (m173 pattern).
__global__ __launch_bounds__(256) void k0(const float* __restrict__ W,
                                          const float* __restrict__ root,
                                          const int* __restrict__ ei,
                                          const int* __restrict__ et,
                                          int* __restrict__ cnt,
                                          unsigned short* __restrict__ WallT_pre) {
    int b = blockIdx.x;
    if (b < COUNT_BLOCKS) {
        int e = b * 256 + threadIdx.x;
        if (e < N_EDGES)
            atomicAdd(&cnt[ei[N_EDGES + e] * N_REL + et[e]], 1);
        return;
    }
    int t = (b - COUNT_BLOCKS) * 256 + threadIdx.x;  // [0, 18432)
    float v; int c, k;
    if (t < N_REL * D_IN * D_OUT) {                  // W: t = (g*128+k)*16+o
        v = W[t];
        int o = t & 15, gk = t >> 4;
        k = gk & 127;
        c = (gk >> 7) * 16 + o;
    } else {                                         // root: u = k*16+o
        int u = t - N_REL * D_IN * D_OUT;
        v = root[u];
        k = u >> 4;
        c = 128 + (u & 15);
    }
    *(unsigned short*)((char*)WallT_pre + swz(c * 256 + k * 2)) = f2bf(v);
}

// -------- k1: MFMA GEMM [64 nodes/block] x [144 cols] --------
// W stage: 9 iterations of linear 16B load + linear ds_write_b128 (source
// pre-swizzled). A-frags: f32 x rows converted in-register. B-frags via swz
// LDS reads. C/D: col=lane&15, row=(lane>>4)*4+j (m89 layout).
__global__ __launch_bounds__(256) void k1(const float* __restrict__ x,
                                          const unsigned short* __restrict__ WallT_pre,
                                          const float* __restrict__ bias,
                                          unsigned short* __restrict__ xW,
                                          float* __restrict__ out) {
    __shared__ unsigned short wlds[NC * D_IN];  // 36864 B
#pragma unroll
    for (int r = 0; r < 9; ++r) {
        int i = r * 256 + threadIdx.x;          // 2304 x 16B chunks
        ((u16x8*)wlds)[i] = ((const u16x8*)WallT_pre)[i];
    }
    __syncthreads();

    int wave = threadIdx.x >> 6, lane = threadIdx.x & 63;
    int n0 = blockIdx.x * 64 + wave * 16;
    if (n0 >= N_NODES) return;
    int col = lane & 15, kg = lane >> 4;

    const float* xrow = x + (size_t)(n0 + col) * D_IN + kg * 8;
    bf16x8 afr[4];
#pragma unroll
    for (int s = 0; s < 4; ++s) {
        float4 lo = *(const float4*)(xrow + s * 32);
        float4 hi = *(const float4*)(xrow + s * 32 + 4);
        bf16x8 f;
        f[0] = (short)f2bf(lo.x); f[1] = (short)f2bf(lo.y);
        f[2] = (short)f2bf(lo.z); f[3] = (short)f2bf(lo.w);
        f[4] = (short)f2bf(hi.x); f[5] = (short)f2bf(hi.y);
        f[6] = (short)f2bf(hi.z); f[7] = (short)f2bf(hi.w);
        afr[s] = f;
    }
    float bv = bias[col];

#pragma unroll
    for (int ct = 0; ct < 9; ++ct) {
        int c = ct * 16 + col;
        f32x4 acc = {0.f, 0.f, 0.f, 0.f};
#pragma unroll
        for (int s = 0; s < 4; ++s) {
            bf16x8 bfr = *(const bf16x8*)((const char*)wlds +
                                          swz(c * 256 + kg * 16 + s * 64));
            acc = __builtin_amdgcn_mfma_f32_16x16x32_bf16(afr[s], bfr, acc, 0, 0, 0);
        }
        if (ct < 8) {
#pragma unroll
            for (int j = 0; j < 4; ++j)
                xW[(size_t)(n0 + kg * 4 + j) * D_IN + ct * 16 + col] = f2bf(acc[j]);
        } else {
#pragma unroll
            for (int j = 0; j < 4; ++j)
                out[(size_t)(n0 + kg * 4 + j) * D_OUT + col] = acc[j] + bv;
        }
    }
}

// -------- edge: out[dst,o] += bf2f(xW[src, rel*16+o]) / cnt[dst,rel] --------
// Round-9-proven: 16 lanes/edge; 16 contiguous edges/slot; int4 index loads;
// 4-edge chunks; plain fire-and-forget f32 atomicAdd.
__global__ __launch_bounds__(256) void edge_k(const unsigned short* __restrict__ xW,
                                              const int* __restrict__ ei,
                                              const int* __restrict__ et,
                                              const int* __restrict__ cnt,
                                              float* __restrict__ out) {
    int wid = (blockIdx.x * 256 + threadIdx.x) >> 6;
    int lane = threadIdx.x & 63;
    int s = lane >> 4, o = lane & 15;
    int e0 = wid * 64 + s * 16;
    if (e0 >= N_EDGES) return;
#pragma unroll 2
    for (int k = 0; k < 4; ++k) {
        int4 s4 = *(const int4*)(ei + e0 + k * 4);
        int4 d4 = *(const int4*)(ei + N_EDGES + e0 + k * 4);
        int4 r4 = *(const int4*)(et + e0 + k * 4);
        float v0 = bf2f(xW[(size_t)s4.x * D_IN + r4.x * D_OUT + o]);
        float v1 = bf2f(xW[(size_t)s4.y * D_IN + r4.y * D_OUT + o]);
        float v2 = bf2f(xW[(size_t)s4.z * D_IN + r4.z * D_OUT + o]);
        float v3 = bf2f(xW[(size_t)s4.w * D_IN + r4.w * D_OUT + o]);
        float c0 = (float)cnt[d4.x * N_REL + r4.x];
        float c1 = (float)cnt[d4.y * N_REL + r4.y];
        float c2 = (float)cnt[d4.z * N_REL + r4.z];
        float c3 = (float)cnt[d4.w * N_REL + r4.w];
        atomicAdd(&out[(size_t)d4.x * D_OUT + o], v0 * __builtin_amdgcn_rcpf(c0));
        atomicAdd(&out[(size_t)d4.y * D_OUT + o], v1 * __builtin_amdgcn_rcpf(c1));
        atomicAdd(&out[(size_t)d4.z * D_OUT + o], v2 * __builtin_amdgcn_rcpf(c2));
        atomicAdd(&out[(size_t)d4.w * D_OUT + o], v3 * __builtin_amdgcn_rcpf(c3));
    }
}

extern "C" void kernel_launch(void* const* d_in, const int* in_sizes, int n_in,
                              void* d_out, int out_size, void* d_ws, size_t ws_size,
                              hipStream_t stream) {
    const float* x    = (const float*)d_in[0];
    const float* W    = (const float*)d_in[1];
    const float* root = (const float*)d_in[2];
    const float* bias = (const float*)d_in[3];
    const int* ei     = (const int*)d_in[4];
    const int* et     = (const int*)d_in[5];
    float* out = (float*)d_out;

    char* ws = (char*)d_ws;
    int* cnt = (int*)ws;                          ws += (size_t)N_NODES * N_REL * 4;  // 1.6 MB
    unsigned short* xW = (unsigned short*)ws;     ws += (size_t)N_NODES * D_IN * 2;   // 12.8 MB
    unsigned short* WallT_pre = (unsigned short*)ws;                                  // 36.9 KB

    hipMemsetAsync(cnt, 0, (size_t)N_NODES * N_REL * 4, stream);
    k0<<<K0_BLOCKS, 256, 0, stream>>>(W, root, ei, et, cnt, WallT_pre);
    k1<<<GEMM_BLOCKS, 256, 0, stream>>>(x, WallT_pre, bias, xW, out);
    edge_k<<<EDGE_BLOCKS, 256, 0, stream>>>(xW, ei, et, cnt, out);
}